// Round 5
// baseline (2910.418 us; speedup 1.0000x reference)
//
#include <hip/hip_runtime.h>
#include <hip/hip_bf16.h>

// GGNN: 5-step gated graph NN on MI355X.
// Round 5 (resubmission; rounds 1-4 all failed on GPU acquisition, no data).
// Split-bf16 MFMA GEMM (hi/lo decomposition, f32-class accuracy).
// Pipeline per call:
//   CSR build (hist -> scan -> scatter) + weight split/transpose to bf16 hi/lo
//   embed -> annot GEMM -> initial state (padded to 256)
//   5x { msg GEMM -> CSR edge-gather -> 4x chunk(gi GEMM, gh GEMM, GRU elem) }
// State ping-pongs state0(ws) <-> d_out; step 5 lands in d_out.

#define N_   50000
#define L_   8
#define E_   800000
#define ND_  256      // NODE_DIM
#define TD_  128      // TOKEN_DIM
#define TYD_ 64       // TYPE_DIM
#define AD_  192      // ANNOT_DIM
#define MD_  128      // MSG_DIM
#define STEPS_ 5      // n_steps device-resident; fixed 5 (graph needs constant work)

typedef __attribute__((ext_vector_type(8))) __bf16 bf16x8;
typedef __attribute__((ext_vector_type(4))) float  f32x4;

// ---------------------------------------------------------------- CSR build
__global__ __launch_bounds__(256) void k_hist(const int* __restrict__ rows,
                                              const float* __restrict__ vals,
                                              int* __restrict__ cnt,
                                              float* __restrict__ divider, int e_total) {
    int e = blockIdx.x * 256 + threadIdx.x;
    if (e >= e_total) return;
    int r = rows[e];
    atomicAdd(&cnt[r], 1);
    atomicAdd(&divider[r], vals[e]);
}

__global__ __launch_bounds__(1024) void k_scan(const int* __restrict__ cnt,
                                               int* __restrict__ row_start, int n) {
    __shared__ int s[1024];
    __shared__ int carry_s;
    int tid = threadIdx.x;
    if (tid == 0) carry_s = 0;
    __syncthreads();
    for (int base = 0; base < n; base += 1024) {
        int x = (base + tid < n) ? cnt[base + tid] : 0;
        s[tid] = x;
        __syncthreads();
        for (int off = 1; off < 1024; off <<= 1) {
            int t = (tid >= off) ? s[tid - off] : 0;
            __syncthreads();
            s[tid] += t;
            __syncthreads();
        }
        int carry = carry_s;
        if (base + tid < n) row_start[base + tid] = carry + s[tid] - x;  // exclusive
        __syncthreads();
        if (tid == 1023) carry_s = carry + s[1023];
        __syncthreads();
    }
    if (tid == 0) row_start[n] = carry_s;
}

__global__ __launch_bounds__(256) void k_seed(const int* __restrict__ rs,
                                              int* __restrict__ cursor, int n) {
    int i = blockIdx.x * 256 + threadIdx.x;
    if (i < n) cursor[i] = rs[i];
}

__global__ __launch_bounds__(256) void k_scatter(const int* __restrict__ rows,
                                                 const int* __restrict__ cols,
                                                 const float* __restrict__ vals,
                                                 int* __restrict__ cursor,
                                                 int* __restrict__ edst,
                                                 float* __restrict__ ew, int e_total) {
    int e = blockIdx.x * 256 + threadIdx.x;
    if (e >= e_total) return;
    int r = rows[e];
    int p = atomicAdd(&cursor[r], 1);
    edst[p] = cols[e];
    ew[p]   = vals[e];
}

// ---------------------------------------------------------------- weight prep
// split f32 -> bf16 hi + bf16 lo (residual), output layout [J][K] (k-minor)
__global__ __launch_bounds__(256) void k_wsplit_d(const float* __restrict__ src,
                                                  __bf16* __restrict__ hi,
                                                  __bf16* __restrict__ lo, int total) {
    int t = blockIdx.x * 256 + threadIdx.x;
    if (t >= total) return;
    float w = src[t];
    __bf16 h = (__bf16)w;
    hi[t] = h;
    lo[t] = (__bf16)(w - (float)h);
}

// src is [K][J] row-major; dst hi/lo are [J][K]
__global__ __launch_bounds__(256) void k_wsplit_t(const float* __restrict__ src,
                                                  __bf16* __restrict__ hi,
                                                  __bf16* __restrict__ lo, int K, int J) {
    int t = blockIdx.x * 256 + threadIdx.x;
    if (t >= K * J) return;
    int j = t / K, k = t - j * K;
    float w = src[(size_t)k * J + j];
    __bf16 h = (__bf16)w;
    hi[t] = h;
    lo[t] = (__bf16)(w - (float)h);
}

// ---------------------------------------------------------------- embed
__global__ __launch_bounds__(256) void k_embed(const int* __restrict__ node_tokens,
                                               const float* __restrict__ mask,
                                               const int* __restrict__ var_type,
                                               const float* __restrict__ tok_emb,
                                               const float* __restrict__ type_emb,
                                               float* __restrict__ annot_in) {
    int t = blockIdx.x * 256 + threadIdx.x;
    if (t >= N_ * AD_) return;
    int n = t / AD_, d = t - n * AD_;
    float v;
    if (d < TD_) {
        v = 0.f;
#pragma unroll
        for (int l = 0; l < L_; l++) {
            int idx = node_tokens[n * L_ + l];
            v += tok_emb[idx * TD_ + d] * mask[n * L_ + l];
        }
    } else {
        v = type_emb[var_type[n] * TYD_ + (d - TD_)];
    }
    annot_in[t] = v;
}

// ---------------------------------------------------------------- MFMA GEMM (split-bf16)
// OUT[M][J](ldout) = A[M][K](lda,f32) @ W^T + bias, where Whi/Wlo are bf16 [J][K].
// acc = Ahi*Whi + Alo*Whi + Ahi*Wlo  (drop lo*lo; ~2^-17 relative error).
// Block 64x128, BK=32, 4 waves (2x2), wave tile 32x64, mfma_f32_16x16x32_bf16.
// LDS granule swizzle: slot = kgran ^ (row&3)   (same XOR on write and read).
__global__ __launch_bounds__(256) void k_gemm_mfma(
        const float* __restrict__ A, int lda,
        const __bf16* __restrict__ Whi, const __bf16* __restrict__ Wlo,
        const float* __restrict__ bias,
        float* __restrict__ OUT, int ldout,
        int M, int K, int J) {
    __shared__ __align__(16) __bf16 sAhi[64 * 32];
    __shared__ __align__(16) __bf16 sAlo[64 * 32];
    __shared__ __align__(16) __bf16 sWhi[128 * 32];
    __shared__ __align__(16) __bf16 sWlo[128 * 32];

    int tid  = threadIdx.x;
    int m0   = blockIdx.x * 64;
    int j0   = blockIdx.y * 128;
    int lane = tid & 63;
    int wv   = tid >> 6;             // wave 0..3
    int wm   = (wv >> 1) * 32;       // wave row offset
    int wn   = (wv & 1) * 64;        // wave col offset
    int l15  = lane & 15;
    int lg   = lane >> 4;            // k-granule group 0..3
    int sl   = lg ^ (l15 & 3);       // swizzled slot for fragment reads

    // A staging: thread -> (row ar, k-granule akg)
    int ar  = tid >> 2, akg = tid & 3;
    int aoff = ar * 32 + (akg ^ (ar & 3)) * 8;
    const float* asrc = A + (size_t)(m0 + ar) * lda + akg * 8;
    bool arow_ok = (m0 + ar) < M;

    // W staging: thread -> j-row (t>>1), two k-granules
    int wj = tid >> 1;
    bool wrow_ok = (j0 + wj) < J;
    size_t wbase = (size_t)(j0 + wj) * K;

    f32x4 acc[2][4];
#pragma unroll
    for (int mi = 0; mi < 2; mi++)
#pragma unroll
        for (int nf = 0; nf < 4; nf++) {
            acc[mi][nf][0] = 0.f; acc[mi][nf][1] = 0.f;
            acc[mi][nf][2] = 0.f; acc[mi][nf][3] = 0.f;
        }

    for (int kk = 0; kk < K; kk += 32) {
        {   // ---- stage A tile 64x32: f32 -> hi/lo bf16 ----
            float v[8];
            if (arow_ok) {
                float4 p0 = *(const float4*)(asrc + kk);
                float4 p1 = *(const float4*)(asrc + kk + 4);
                v[0] = p0.x; v[1] = p0.y; v[2] = p0.z; v[3] = p0.w;
                v[4] = p1.x; v[5] = p1.y; v[6] = p1.z; v[7] = p1.w;
            } else {
#pragma unroll
                for (int q = 0; q < 8; q++) v[q] = 0.f;
            }
            bf16x8 hiv, lov;
#pragma unroll
            for (int q = 0; q < 8; q++) {
                __bf16 h = (__bf16)v[q];
                hiv[q] = h;
                lov[q] = (__bf16)(v[q] - (float)h);
            }
            *(bf16x8*)&sAhi[aoff] = hiv;
            *(bf16x8*)&sAlo[aoff] = lov;
        }
        // ---- stage W tile 128x32 (pre-split bf16, [J][K] source) ----
#pragma unroll
        for (int h = 0; h < 2; h++) {
            int kg   = (tid & 1) * 2 + h;
            int off  = wj * 32 + (kg ^ (wj & 3)) * 8;
            bf16x8 hv, lv;
            if (wrow_ok) {
                hv = *(const bf16x8*)(Whi + wbase + kk + kg * 8);
                lv = *(const bf16x8*)(Wlo + wbase + kk + kg * 8);
            } else {
#pragma unroll
                for (int q = 0; q < 8; q++) { hv[q] = (__bf16)0.f; lv[q] = (__bf16)0.f; }
            }
            *(bf16x8*)&sWhi[off] = hv;
            *(bf16x8*)&sWlo[off] = lv;
        }
        __syncthreads();
        // ---- fragments + MFMA ----
        bf16x8 ah[2], al[2], bh[4], bl[4];
#pragma unroll
        for (int mi = 0; mi < 2; mi++) {
            int idx = (wm + mi * 16 + l15) * 32 + sl * 8;
            ah[mi] = *(bf16x8*)&sAhi[idx];
            al[mi] = *(bf16x8*)&sAlo[idx];
        }
#pragma unroll
        for (int nf = 0; nf < 4; nf++) {
            int idx = (wn + nf * 16 + l15) * 32 + sl * 8;
            bh[nf] = *(bf16x8*)&sWhi[idx];
            bl[nf] = *(bf16x8*)&sWlo[idx];
        }
#pragma unroll
        for (int mi = 0; mi < 2; mi++)
#pragma unroll
            for (int nf = 0; nf < 4; nf++) {
                acc[mi][nf] = __builtin_amdgcn_mfma_f32_16x16x32_bf16(ah[mi], bh[nf], acc[mi][nf], 0, 0, 0);
                acc[mi][nf] = __builtin_amdgcn_mfma_f32_16x16x32_bf16(al[mi], bh[nf], acc[mi][nf], 0, 0, 0);
                acc[mi][nf] = __builtin_amdgcn_mfma_f32_16x16x32_bf16(ah[mi], bl[nf], acc[mi][nf], 0, 0, 0);
            }
        __syncthreads();
    }
    // ---- epilogue: C/D map col=lane&15, row=(lane>>4)*4+reg (verified m89) ----
#pragma unroll
    for (int mi = 0; mi < 2; mi++) {
        int gmb = m0 + wm + mi * 16 + lg * 4;
#pragma unroll
        for (int nf = 0; nf < 4; nf++) {
            int gj = j0 + wn + nf * 16 + l15;
            if (gj >= J) continue;
            float bs = bias[gj];
#pragma unroll
            for (int r2 = 0; r2 < 4; r2++) {
                int gm = gmb + r2;
                if (gm < M) OUT[(size_t)gm * ldout + gj] = acc[mi][nf][r2] + bs;
            }
        }
    }
}

// ---------------------------------------------------------------- edge gather/reduce (CSR)
__global__ __launch_bounds__(128) void k_edge(const int* __restrict__ row_start,
                                              const int* __restrict__ edge_dst,
                                              const float* __restrict__ edge_w,
                                              const float* __restrict__ msg_out,
                                              const float* __restrict__ divider,
                                              float* __restrict__ msg_in) {
    int n = blockIdx.x;
    int d = threadIdx.x;
    int s = row_start[n], e = row_start[n + 1];
    float acc = 0.f;
    for (int i = s; i < e; i++) {
        int c = edge_dst[i];          // uniform across block -> scalar load
        float v = edge_w[i];
        acc += msg_out[(size_t)c * MD_ + d] * v;
    }
    float dv = divider[n];
    dv = dv < 1.f ? 1.f : dv;
    msg_in[(size_t)n * MD_ + d] = acc / dv;
}

// ---------------------------------------------------------------- GRU elementwise
__global__ __launch_bounds__(256) void k_gru_elem(const float* __restrict__ gi,
                                                  const float* __restrict__ gh,
                                                  const float* __restrict__ st_in,
                                                  float* __restrict__ st_out, int M) {
    int t = blockIdx.x * 256 + threadIdx.x;
    if (t >= M * ND_) return;
    int n = t >> 8, h = t & 255;
    const float* gir = gi + (size_t)n * 768;
    const float* ghr = gh + (size_t)n * 768;
    float i_r = gir[h], i_z = gir[256 + h], i_n = gir[512 + h];
    float h_r = ghr[h], h_z = ghr[256 + h], h_n = ghr[512 + h];
    float r = 1.f / (1.f + expf(-(i_r + h_r)));
    float z = 1.f / (1.f + expf(-(i_z + h_z)));
    float nn = tanhf(i_n + r * h_n);
    float hp = st_in[t];
    st_out[t] = (1.f - z) * nn + z * hp;
}

// ---------------------------------------------------------------- launch
extern "C" void kernel_launch(void* const* d_in, const int* in_sizes, int n_in,
                              void* d_out, int out_size, void* d_ws, size_t ws_size,
                              hipStream_t stream) {
    const int*   var_type    = (const int*)  d_in[0];
    const int*   node_tokens = (const int*)  d_in[1];
    const float* mask        = (const float*)d_in[2];
    const int*   adj_rows    = (const int*)  d_in[3];
    const int*   adj_cols    = (const int*)  d_in[4];
    const float* adj_vals    = (const float*)d_in[5];
    // d_in[6] = n_steps (device scalar; fixed 5, see STEPS_)
    const float* tok_emb     = (const float*)d_in[7];
    const float* type_emb    = (const float*)d_in[8];
    const float* sg_w        = (const float*)d_in[9];
    const float* sg_b        = (const float*)d_in[10];
    const float* msg_w       = (const float*)d_in[11];
    const float* msg_b       = (const float*)d_in[12];
    const float* w_ih        = (const float*)d_in[13];
    const float* w_hh        = (const float*)d_in[14];
    const float* b_ih        = (const float*)d_in[15];
    const float* b_hh        = (const float*)d_in[16];
    float* out = (float*)d_out;

    // workspace layout (all regions 16B-aligned; total ~189 MB)
    float* f = (float*)d_ws;
    float* state0   = f;        f += (size_t)N_ * 256;   // 51.2 MB
    float* msg_out  = f;        f += (size_t)N_ * 512;   // 102.4 MB (also annot & gi/gh scratch)
    float* msg_in   = f;        f += (size_t)N_ * 128;   // 25.6 MB
    float* divider  = f;        f += N_;
    int*   row_start= (int*)f;  f += N_ + 4;
    int*   cursor   = (int*)f;  f += N_;
    int*   edge_dst = (int*)f;  f += E_;
    float* edge_w   = f;        f += E_;
    // bf16 hi/lo weight arrays ([J][K] layout); sizes all multiples of 8 shorts
    __bf16* sgw_hi  = (__bf16*)f;            // 192*192
    __bf16* sgw_lo  = sgw_hi + 192 * 192;
    __bf16* msgw_hi = sgw_lo + 192 * 192;    // 512*256
    __bf16* msgw_lo = msgw_hi + 512 * 256;
    __bf16* wih_hi  = msgw_lo + 512 * 256;   // 768*128
    __bf16* wih_lo  = wih_hi + 768 * 128;
    __bf16* whh_hi  = wih_lo + 768 * 128;    // 768*256
    __bf16* whh_lo  = whh_hi + 768 * 256;

    // zero: divider + row_start + cursor (contiguous), and state0 (pad cols stay 0)
    hipMemsetAsync(divider, 0, (size_t)(N_ + (N_ + 4) + N_) * sizeof(float), stream);
    hipMemsetAsync(state0, 0, (size_t)N_ * 256 * sizeof(float), stream);

    // CSR build + divider
    k_hist<<<(E_ + 255) / 256, 256, 0, stream>>>(adj_rows, adj_vals, cursor, divider, E_);
    k_scan<<<1, 1024, 0, stream>>>(cursor, row_start, N_);
    k_seed<<<(N_ + 255) / 256, 256, 0, stream>>>(row_start, cursor, N_);
    k_scatter<<<(E_ + 255) / 256, 256, 0, stream>>>(adj_rows, adj_cols, adj_vals,
                                                    cursor, edge_dst, edge_w, E_);
    // weight split/transpose to bf16 hi/lo [J][K]
    k_wsplit_t<<<(192 * 192 + 255) / 256, 256, 0, stream>>>(sg_w, sgw_hi, sgw_lo, 192, 192);
    k_wsplit_t<<<(256 * 512 + 255) / 256, 256, 0, stream>>>(msg_w, msgw_hi, msgw_lo, 256, 512);
    k_wsplit_d<<<(768 * 128 + 255) / 256, 256, 0, stream>>>(w_ih, wih_hi, wih_lo, 768 * 128);
    k_wsplit_d<<<(768 * 256 + 255) / 256, 256, 0, stream>>>(w_hh, whh_hi, whh_lo, 768 * 256);

    // initial annotation -> state0[:, :192]
    float* annot_in = msg_out;  // scratch (N*192 <= N*512)
    k_embed<<<(N_ * AD_ + 255) / 256, 256, 0, stream>>>(node_tokens, mask, var_type,
                                                        tok_emb, type_emb, annot_in);
    {
        dim3 g((N_ + 63) / 64, 2);   // J=192 -> 2 j-blocks (guarded)
        k_gemm_mfma<<<g, 256, 0, stream>>>(annot_in, AD_, sgw_hi, sgw_lo, sg_b,
                                           state0, 256, N_, AD_, AD_);
    }

    // 5 propagation steps; state ping-pongs state0 <-> out (final lands in out)
    for (int s = 0; s < STEPS_; s++) {
        float* cur = (s & 1) ? out : state0;
        float* nxt = (s & 1) ? state0 : out;

        {   // msg_out[N,512] = cur @ msg_w + msg_b
            dim3 g((N_ + 63) / 64, 4);
            k_gemm_mfma<<<g, 256, 0, stream>>>(cur, 256, msgw_hi, msgw_lo, msg_b,
                                               msg_out, 512, N_, 256, 512);
        }
        // msg_in[N,128] = (CSR-gather of msg_out rows) / divider
        k_edge<<<N_, 128, 0, stream>>>(row_start, edge_dst, edge_w, msg_out, divider, msg_in);

        // GRU in 4 node-chunks of 12500: gi+gh = 2*38.4 MB fits in msg_out (102.4 MB)
        // without touching msg_in.
        for (int c = 0; c < 4; c++) {
            int c0 = c * 12500;
            const int Mc = 12500;
            float* gi = msg_out;                        // [Mc,768]
            float* gh = msg_out + (size_t)12500 * 768;  // [Mc,768]
            dim3 g((Mc + 63) / 64, 6);
            k_gemm_mfma<<<g, 256, 0, stream>>>(msg_in + (size_t)c0 * 128, 128,
                                               wih_hi, wih_lo, b_ih, gi, 768, Mc, 128, 768);
            k_gemm_mfma<<<g, 256, 0, stream>>>(cur + (size_t)c0 * 256, 256,
                                               whh_hi, whh_lo, b_hh, gh, 768, Mc, 256, 768);
            k_gru_elem<<<(Mc * 256 + 255) / 256, 256, 0, stream>>>(
                gi, gh, cur + (size_t)c0 * 256, nxt + (size_t)c0 * 256, Mc);
        }
    }
}